// Round 2
// baseline (287.399 us; speedup 1.0000x reference)
//
#include <hip/hip_runtime.h>
#include <hip/hip_bf16.h>

namespace {
constexpr int T_LEN = 8192;   // T
constexpr int C_CH  = 512;    // C
constexpr int B_SZ  = 8;      // B
constexpr int TILE  = 2048;   // x-samples per block
constexpr int NTH   = 256;    // threads per block
constexpr int TPR   = T_LEN / TILE;   // tiles per row = 4
constexpr int NS    = TILE + 6;       // z-pairs computed per tile (s in [n0-3, n0+TILE+2])
constexpr int XSZ   = TILE + 12;      // x tile + 6 halo each side
constexpr int ZSZ   = 2 * TILE + 12;  // z tile, base index m0 = 2*n0 - 6
}

// Fused: upsample-by-2 (12-tap polyphase) -> snake-beta -> downsample-by-2 (12-tap).
// Derivation (UP=DOWN=2, K=12):
//   y[2s]   = 2*sum_a uf[11-2a] * x[clamp(s-3+a)]   (a=0..5)
//   y[2s+1] = 2*sum_a uf[10-2a] * x[clamp(s-2+a)]
//   z[m]    = y[m] + sin(y[m]*e^alpha)^2 / (e^beta + 1e-9)
//   out[n]  = sum_j df[j] * z[clamp(2n-5+j, 0, 2T-1)]  (j=0..11)
__global__ __launch_bounds__(NTH)
void aaa_fused(const float* __restrict__ x,
               const float* __restrict__ alpha,
               const float* __restrict__ beta,
               const float* __restrict__ upf,
               const float* __restrict__ dnf,
               float* __restrict__ out)
{
    __shared__ float xs[XSZ];
    __shared__ float zs[ZSZ];

    const int tid  = threadIdx.x;
    const int bid  = blockIdx.x;
    const int tile = bid & (TPR - 1);
    const int row  = bid / TPR;          // b*C + c
    const int ch   = row & (C_CH - 1);
    const int n0   = tile * TILE;

    const float* __restrict__ xr = x + (size_t)row * T_LEN;
    float* __restrict__ outr     = out + (size_t)row * T_LEN;

    // per-channel snake constants (broadcast loads)
    const float av = expf(alpha[ch]);
    const float rb = 1.0f / (expf(beta[ch]) + 1e-9f);

    // filter taps into registers (broadcast, L1-hit)
    float cE[6], cO[6], fd[12];
#pragma unroll
    for (int i = 0; i < 6; ++i) {
        cE[i] = 2.0f * upf[11 - 2 * i];
        cO[i] = 2.0f * upf[10 - 2 * i];
    }
#pragma unroll
    for (int i = 0; i < 12; ++i) fd[i] = dnf[i];

    // ---- stage x tile (+6 halo each side, edge-clamped) ----
    for (int i = tid; i < XSZ; i += NTH) {
        int g = n0 - 6 + i;
        g = min(max(g, 0), T_LEN - 1);
        xs[i] = xr[g];
    }
    __syncthreads();

    // ---- phase A: polyphase upsample + snake; z pair per s ----
    // s = n0 - 3 + si ; x[s+d] lives at xs[si + d + 3]
    for (int si = tid; si < NS; si += NTH) {
        const float x0 = xs[si + 0];
        const float x1 = xs[si + 1];
        const float x2 = xs[si + 2];
        const float x3 = xs[si + 3];
        const float x4 = xs[si + 4];
        const float x5 = xs[si + 5];
        const float x6 = xs[si + 6];
        float ye = cE[0]*x0 + cE[1]*x1 + cE[2]*x2 + cE[3]*x3 + cE[4]*x4 + cE[5]*x5;
        float yo = cO[0]*x1 + cO[1]*x2 + cO[2]*x3 + cO[3]*x4 + cO[4]*x5 + cO[5]*x6;
        const float se = sinf(ye * av);
        const float so = sinf(yo * av);
        zs[2 * si + 0] = ye + se * se * rb;   // z[2s]
        zs[2 * si + 1] = yo + so * so * rb;   // z[2s+1]
    }
    __syncthreads();

    // ---- phase B: 12-tap downsample by 2 ----
#pragma unroll
    for (int k = 0; k < TILE / NTH; ++k) {
        const int ln = tid + k * NTH;
        const int n  = n0 + ln;
        float acc = 0.0f;
        if (n >= 3 && n <= T_LEN - 4) {
            // interior: z indices 2n-5 .. 2n+6 all in-row; lds base = 2*ln+1
            const int base = 2 * ln + 1;
#pragma unroll
            for (int j = 0; j < 12; ++j) acc += fd[j] * zs[base + j];
        } else {
            const int m0 = 2 * n0 - 6;
#pragma unroll
            for (int j = 0; j < 12; ++j) {
                int m = 2 * n - 5 + j;
                m = min(max(m, 0), 2 * T_LEN - 1);
                acc += fd[j] * zs[m - m0];
            }
        }
        outr[n] = acc;
    }
}

extern "C" void kernel_launch(void* const* d_in, const int* in_sizes, int n_in,
                              void* d_out, int out_size, void* d_ws, size_t ws_size,
                              hipStream_t stream)
{
    (void)in_sizes; (void)n_in; (void)out_size; (void)d_ws; (void)ws_size;
    const float* x     = (const float*)d_in[0];
    const float* alpha = (const float*)d_in[1];
    const float* beta  = (const float*)d_in[2];
    const float* upf   = (const float*)d_in[3];
    const float* dnf   = (const float*)d_in[4];
    float* out = (float*)d_out;

    dim3 grid(B_SZ * C_CH * TPR);   // 16384 blocks
    dim3 block(NTH);
    aaa_fused<<<grid, block, 0, stream>>>(x, alpha, beta, upf, dnf, out);
}

// Round 4
// 233.966 us; speedup vs baseline: 1.2284x; 1.2284x over previous
//
#include <hip/hip_runtime.h>
#include <hip/hip_bf16.h>

typedef float v2f __attribute__((ext_vector_type(2)));

namespace {
constexpr int T_LEN = 8192;   // T
constexpr int C_CH  = 512;    // C
constexpr int B_SZ  = 8;      // B
constexpr int TILE  = 2048;   // x-samples per block
constexpr int NTH   = 256;    // threads per block
constexpr int TPR   = T_LEN / TILE;   // tiles per row = 4
constexpr int NS    = TILE + 6;       // z-pairs per tile (s in [n0-3, n0+TILE+2])
constexpr int XOFF  = 8;              // xs interior offset (16B-aligned float4 staging)
constexpr int XSZ   = XOFF + TILE + 8;   // halo: xs[2..7] left, xs[XOFF+TILE..+5] right
constexpr int ZSZ   = 2 * TILE + 12;  // z tile, base m0 = 2*n0 - 6
}

// Fused: upsample-by-2 (12-tap polyphase) -> snake-beta -> downsample-by-2 (12-tap).
//   y[2s]   = 2*sum_a uf[11-2a] * x[clamp(s-3+a)]   (a=0..5)
//   y[2s+1] = 2*sum_a uf[10-2a] * x[clamp(s-2+a)]
//   z[m]    = y[m] + sin(y[m]*e^alpha)^2 / (e^beta+1e-9)
//           = y[m] + (1 - cos(2*y[m]*a)) * rb/2          (half-angle, hw v_cos)
//   out[n]  = sum_j df[j] * z[clamp(2n-5+j)]
//           = sum_{k=0..6} w[k] (.) float2{z[2n-6+2k], z[2n-5+2k]}   (packed form)
//     with w[0]={0,df[0]}, w[k]={df[2k-1],df[2k]} (df[12]:=0)
__global__ __launch_bounds__(NTH)
void aaa_fused(const float* __restrict__ x,
               const float* __restrict__ alpha,
               const float* __restrict__ beta,
               const float* __restrict__ upf,
               const float* __restrict__ dnf,
               float* __restrict__ out)
{
    __shared__ __align__(16) float xs[XSZ];
    __shared__ __align__(16) float zs[ZSZ];

    const int tid  = threadIdx.x;
    const int bid  = blockIdx.x;
    const int tile = bid & (TPR - 1);
    const int row  = bid / TPR;          // b*C + c
    const int ch   = row & (C_CH - 1);
    const int n0   = tile * TILE;

    const float* __restrict__ xr = x + (size_t)row * T_LEN;
    float* __restrict__ outr     = out + (size_t)row * T_LEN;

    // per-channel snake constants (broadcast loads)
    const float av  = expf(alpha[ch]);
    const float rb  = 1.0f / (expf(beta[ch]) + 1e-9f);
    const float avp = av * 0.3183098861837907f;  // a/pi: cos(2*a*y) = cos2pi(y*avp)
    const float hrb = 0.5f * rb;

    // filter taps into registers (broadcast, L1-hit)
    float cE[6], cO[6];
#pragma unroll
    for (int i = 0; i < 6; ++i) {
        cE[i] = 2.0f * upf[11 - 2 * i];
        cO[i] = 2.0f * upf[10 - 2 * i];
    }
    v2f w[7];
    w[0] = v2f{0.0f, dnf[0]};
#pragma unroll
    for (int k = 1; k < 6; ++k) w[k] = v2f{dnf[2 * k - 1], dnf[2 * k]};
    w[6] = v2f{dnf[11], 0.0f};

    // ---- stage x tile: interior float4, halos scalar (edge-clamped) ----
    {
        const float4* __restrict__ xr4 = reinterpret_cast<const float4*>(xr + n0);
        float4* xs4 = reinterpret_cast<float4*>(xs + XOFF);
        xs4[tid]       = xr4[tid];
        xs4[tid + NTH] = xr4[tid + NTH];
        if (tid < 6) {
            int gl = max(n0 - 6 + tid, 0);
            xs[XOFF - 6 + tid] = xr[gl];
            int gr = min(n0 + TILE + tid, T_LEN - 1);
            xs[XOFF + TILE + tid] = xr[gr];
        }
    }
    __syncthreads();

    // ---- phase A: polyphase upsample + snake (half-angle hw cos) ----
    // s = n0 - 3 + si ; x[s-3+d] = x[n0-6+si+d] lives at xs[XOFF-6 + si + d] = xs[si + d + 2]
    for (int si = tid; si < NS; si += NTH) {
        const float x0 = xs[si + 2];
        const float x1 = xs[si + 3];
        const float x2 = xs[si + 4];
        const float x3 = xs[si + 5];
        const float x4 = xs[si + 6];
        const float x5 = xs[si + 7];
        const float x6 = xs[si + 8];
        float ye = cE[0]*x0 + cE[1]*x1 + cE[2]*x2 + cE[3]*x3 + cE[4]*x4 + cE[5]*x5;
        float yo = cO[0]*x1 + cO[1]*x2 + cO[2]*x3 + cO[3]*x4 + cO[4]*x5 + cO[5]*x6;
        float ue = ye * avp;  ue -= floorf(ue);          // revolutions, range-reduced
        float uo = yo * avp;  uo -= floorf(uo);
        const float ce = __builtin_amdgcn_cosf(ue);      // v_cos_f32 (rev input)
        const float co = __builtin_amdgcn_cosf(uo);
        const float z0 = (ye + hrb) - hrb * ce;          // y + (1-cos)/2 * rb
        const float z1 = (yo + hrb) - hrb * co;
        reinterpret_cast<v2f*>(zs)[si] = v2f{z0, z1};    // b64 store, 2-way free
    }
    __syncthreads();

    // ---- phase B: 12-tap downsample by 2, packed float2 form ----
    const v2f* __restrict__ zs2 = reinterpret_cast<const v2f*>(zs);
#pragma unroll
    for (int k = 0; k < TILE / NTH; ++k) {
        const int ln = tid + k * NTH;
        const int n  = n0 + ln;
        if (n >= 3 && n <= T_LEN - 4) {
            // interior: zs2[ln+j] = {z[2n-6+2j], z[2n-5+2j]}, j=0..6
            v2f acc = w[0] * zs2[ln];
#pragma unroll
            for (int j = 1; j < 7; ++j) acc += w[j] * zs2[ln + j];  // v_pk_fma_f32
            outr[n] = acc.x + acc.y;
        } else {
            const int m0 = 2 * n0 - 6;
            float acc = 0.0f;
#pragma unroll
            for (int j = 0; j < 12; ++j) {
                int m = 2 * n - 5 + j;
                m = min(max(m, 0), 2 * T_LEN - 1);
                // scalar tap: j odd -> w[(j+1)/2].x, j even -> w[j/2].y
                const float fj = (j & 1) ? w[(j + 1) >> 1].x : w[j >> 1].y;
                acc += fj * zs[m - m0];
            }
            outr[n] = acc;
        }
    }
}

extern "C" void kernel_launch(void* const* d_in, const int* in_sizes, int n_in,
                              void* d_out, int out_size, void* d_ws, size_t ws_size,
                              hipStream_t stream)
{
    (void)in_sizes; (void)n_in; (void)out_size; (void)d_ws; (void)ws_size;
    const float* x     = (const float*)d_in[0];
    const float* alpha = (const float*)d_in[1];
    const float* beta  = (const float*)d_in[2];
    const float* upf   = (const float*)d_in[3];
    const float* dnf   = (const float*)d_in[4];
    float* out = (float*)d_out;

    dim3 grid(B_SZ * C_CH * TPR);   // 16384 blocks
    dim3 block(NTH);
    aaa_fused<<<grid, block, 0, stream>>>(x, alpha, beta, upf, dnf, out);
}